// Round 1
// baseline (1062.707 us; speedup 1.0000x reference)
//
#include <hip/hip_runtime.h>
#include <hip/hip_bf16.h>
#include <math.h>

#define D_IN   256
#define HD     128     // N_HEADS * D_OUT
#define NHEAD  4
#define DOUT   32
#define NEG_SLOPE 0.2f
#define BK 64

// ---------------- init: out = bias broadcast, m = -inf, denom = 0 ----------------
__global__ void init_k(float* __restrict__ out, const float* __restrict__ bias,
                       float* __restrict__ m, float* __restrict__ denom, int N) {
    int i = blockIdx.x * 256 + threadIdx.x;
    if (i < N * HD) out[i] = bias[i & (HD - 1)];
    if (i < N * NHEAD) {
        m[i] = __int_as_float(0xFF800000);  // -inf
        denom[i] = 0.0f;
    }
}

// ---------------- GEMM h = feat @ W^T  (+ fused el/er) ----------------
// block: 256 threads, 32 nodes per block. thread (tx,ty): tx=t&31, ty=t>>5
// channel mapping: ch = j*32 + tx  (j = head index 0..3), node = n0 + ty*4 + i
__global__ __launch_bounds__(256) void gemm_k(
        const float* __restrict__ feat, const float* __restrict__ fcw,
        const float* __restrict__ attn_l, const float* __restrict__ attn_r,
        float* __restrict__ hbuf, float* __restrict__ el, float* __restrict__ er,
        int N) {
    __shared__ float sf[32][BK + 4];
    __shared__ float sw[HD][BK + 4];
    const int t  = threadIdx.x;
    const int tx = t & 31;
    const int ty = t >> 5;
    const int n0 = blockIdx.x * 32;

    float acc[4][4] = {};   // [node i][head j]

    for (int k0 = 0; k0 < D_IN; k0 += BK) {
        // stage feat tile: 32 x BK = 512 float4, 2 per thread
        #pragma unroll
        for (int it = 0; it < 2; ++it) {
            int i = t + it * 256;
            int row = i >> 4, c4 = i & 15;
            float4 v = make_float4(0.f, 0.f, 0.f, 0.f);
            if (n0 + row < N)
                v = *(const float4*)&feat[(size_t)(n0 + row) * D_IN + k0 + c4 * 4];
            *(float4*)&sf[row][c4 * 4] = v;
        }
        // stage w tile: 128 x BK = 2048 float4, 8 per thread
        #pragma unroll
        for (int it = 0; it < 8; ++it) {
            int i = t + it * 256;
            int row = i >> 4, c4 = i & 15;
            float4 v = *(const float4*)&fcw[(size_t)row * D_IN + k0 + c4 * 4];
            *(float4*)&sw[row][c4 * 4] = v;
        }
        __syncthreads();
        #pragma unroll
        for (int k = 0; k < BK; k += 4) {
            float4 fv[4], wv[4];
            #pragma unroll
            for (int i = 0; i < 4; ++i) fv[i] = *(const float4*)&sf[ty * 4 + i][k];
            #pragma unroll
            for (int j = 0; j < 4; ++j) wv[j] = *(const float4*)&sw[j * 32 + tx][k];
            #pragma unroll
            for (int i = 0; i < 4; ++i)
                #pragma unroll
                for (int j = 0; j < 4; ++j)
                    acc[i][j] += fv[i].x * wv[j].x + fv[i].y * wv[j].y
                               + fv[i].z * wv[j].z + fv[i].w * wv[j].w;
        }
        __syncthreads();
    }

    // attention vectors for this lane's channel in each head
    float al[4], ar[4];
    #pragma unroll
    for (int j = 0; j < 4; ++j) {
        al[j] = attn_l[j * 32 + tx];
        ar[j] = attn_r[j * 32 + tx];
    }

    #pragma unroll
    for (int i = 0; i < 4; ++i) {
        int node = n0 + ty * 4 + i;
        bool ok = node < N;
        // store h row (channels j*32+tx)
        if (ok) {
            #pragma unroll
            for (int j = 0; j < 4; ++j)
                hbuf[(size_t)node * HD + j * 32 + tx] = acc[i][j];
        }
        // el/er: reduce over the 32 lanes (d dimension) per head
        #pragma unroll
        for (int j = 0; j < 4; ++j) {
            float vl = acc[i][j] * al[j];
            float vr = acc[i][j] * ar[j];
            #pragma unroll
            for (int o = 1; o < 32; o <<= 1) {
                vl += __shfl_xor(vl, o);
                vr += __shfl_xor(vr, o);
            }
            if (tx == 0 && ok) {
                el[node * NHEAD + j] = vl;
                er[node * NHEAD + j] = vr;
            }
        }
    }
}

// ---------------- edge max (segment_max over dst) ----------------
__device__ __forceinline__ float edge_logit(const float* el, const float* er,
                                            int s, int d, int hh) {
    float v = el[s * NHEAD + hh] + er[d * NHEAD + hh];
    return v > 0.f ? v : NEG_SLOPE * v;
}

__global__ void edge_max_k(const int* __restrict__ src, const int* __restrict__ dst,
                           const float* __restrict__ el, const float* __restrict__ er,
                           float* __restrict__ m, int E) {
    int i = blockIdx.x * 256 + threadIdx.x;
    if (i >= E * NHEAD) return;
    int e = i >> 2, hh = i & 3;
    int s = src[e], d = dst[e];
    float v = edge_logit(el, er, s, d, hh);
    float* addr = &m[d * NHEAD + hh];
    if (v >= 0.f) atomicMax((int*)addr, __float_as_int(v));
    else          atomicMin((unsigned int*)addr, __float_as_uint(v));
}

// ---------------- edge exp + denom (segment_sum over dst) ----------------
__global__ void edge_den_k(const int* __restrict__ src, const int* __restrict__ dst,
                           const float* __restrict__ el, const float* __restrict__ er,
                           const float* __restrict__ m, float* __restrict__ denom, int E) {
    int i = blockIdx.x * 256 + threadIdx.x;
    if (i >= E * NHEAD) return;
    int e = i >> 2, hh = i & 3;
    int s = src[e], d = dst[e];
    float v = edge_logit(el, er, s, d, hh);
    float ex = expf(v - m[d * NHEAD + hh]);
    atomicAdd(&denom[d * NHEAD + hh], ex);
}

// ---------------- aggregate: out[dst] += h[src] * a ----------------
__global__ void aggregate_k(const int* __restrict__ src, const int* __restrict__ dst,
                            const float* __restrict__ el, const float* __restrict__ er,
                            const float* __restrict__ m, const float* __restrict__ denom,
                            const float* __restrict__ hbuf, float* __restrict__ out, int E) {
    int i = blockIdx.x * 256 + threadIdx.x;
    if (i >= E * HD) return;
    int e = i >> 7, c = i & (HD - 1);
    int hh = c >> 5;
    int s = src[e], d = dst[e];
    float v = edge_logit(el, er, s, d, hh);
    float ex = expf(v - m[d * NHEAD + hh]);
    float a = ex / fmaxf(denom[d * NHEAD + hh], 1e-9f);
    atomicAdd(&out[(size_t)d * HD + c], hbuf[(size_t)s * HD + c] * a);
}

extern "C" void kernel_launch(void* const* d_in, const int* in_sizes, int n_in,
                              void* d_out, int out_size, void* d_ws, size_t ws_size,
                              hipStream_t stream) {
    const float* feat   = (const float*)d_in[0];
    const float* fcw    = (const float*)d_in[1];
    const float* attn_l = (const float*)d_in[2];
    const float* attn_r = (const float*)d_in[3];
    const float* bias   = (const float*)d_in[4];
    const int*   src    = (const int*)d_in[5];
    const int*   dst    = (const int*)d_in[6];
    float* out = (float*)d_out;

    const int N = in_sizes[0] / D_IN;
    const int E = in_sizes[5];

    float* hbuf  = (float*)d_ws;                 // N*128
    float* el    = hbuf + (size_t)N * HD;        // N*4
    float* er    = el + (size_t)N * NHEAD;       // N*4
    float* mbuf  = er + (size_t)N * NHEAD;       // N*4
    float* denom = mbuf + (size_t)N * NHEAD;     // N*4

    init_k<<<(N * HD + 255) / 256, 256, 0, stream>>>(out, bias, mbuf, denom, N);
    gemm_k<<<(N + 31) / 32, 256, 0, stream>>>(feat, fcw, attn_l, attn_r, hbuf, el, er, N);
    edge_max_k<<<(E * NHEAD + 255) / 256, 256, 0, stream>>>(src, dst, el, er, mbuf, E);
    edge_den_k<<<(E * NHEAD + 255) / 256, 256, 0, stream>>>(src, dst, el, er, mbuf, denom, E);
    aggregate_k<<<((size_t)E * HD + 255) / 256, 256, 0, stream>>>(src, dst, el, er, mbuf, denom, hbuf, out, E);
}

// Round 2
// 473.844 us; speedup vs baseline: 2.2427x; 2.2427x over previous
//
#include <hip/hip_runtime.h>
#include <hip/hip_bf16.h>
#include <math.h>

#define D_IN   256
#define HD     128     // N_HEADS * D_OUT
#define NHEAD  4
#define NEG_SLOPE 0.2f
#define BK 64
#define CHUNK 64

// ---------------- zero counts & cursors ----------------
__global__ void zero_k(int* __restrict__ counts, int* __restrict__ cursor, int N) {
    int i = blockIdx.x * 256 + threadIdx.x;
    if (i < N) { counts[i] = 0; cursor[i] = 0; }
}

// ---------------- GEMM h = feat @ W^T  (+ fused el/er) ----------------
__global__ __launch_bounds__(256) void gemm_k(
        const float* __restrict__ feat, const float* __restrict__ fcw,
        const float* __restrict__ attn_l, const float* __restrict__ attn_r,
        float* __restrict__ hbuf, float* __restrict__ el, float* __restrict__ er,
        int N) {
    __shared__ float sf[32][BK + 4];
    __shared__ float sw[HD][BK + 4];
    const int t  = threadIdx.x;
    const int tx = t & 31;
    const int ty = t >> 5;
    const int n0 = blockIdx.x * 32;

    float acc[4][4] = {};   // [node i][head j]

    for (int k0 = 0; k0 < D_IN; k0 += BK) {
        #pragma unroll
        for (int it = 0; it < 2; ++it) {
            int i = t + it * 256;
            int row = i >> 4, c4 = i & 15;
            float4 v = make_float4(0.f, 0.f, 0.f, 0.f);
            if (n0 + row < N)
                v = *(const float4*)&feat[(size_t)(n0 + row) * D_IN + k0 + c4 * 4];
            *(float4*)&sf[row][c4 * 4] = v;
        }
        #pragma unroll
        for (int it = 0; it < 8; ++it) {
            int i = t + it * 256;
            int row = i >> 4, c4 = i & 15;
            float4 v = *(const float4*)&fcw[(size_t)row * D_IN + k0 + c4 * 4];
            *(float4*)&sw[row][c4 * 4] = v;
        }
        __syncthreads();
        #pragma unroll
        for (int k = 0; k < BK; k += 4) {
            float4 fv[4], wv[4];
            #pragma unroll
            for (int i = 0; i < 4; ++i) fv[i] = *(const float4*)&sf[ty * 4 + i][k];
            #pragma unroll
            for (int j = 0; j < 4; ++j) wv[j] = *(const float4*)&sw[j * 32 + tx][k];
            #pragma unroll
            for (int i = 0; i < 4; ++i)
                #pragma unroll
                for (int j = 0; j < 4; ++j)
                    acc[i][j] += fv[i].x * wv[j].x + fv[i].y * wv[j].y
                               + fv[i].z * wv[j].z + fv[i].w * wv[j].w;
        }
        __syncthreads();
    }

    float al[4], ar[4];
    #pragma unroll
    for (int j = 0; j < 4; ++j) {
        al[j] = attn_l[j * 32 + tx];
        ar[j] = attn_r[j * 32 + tx];
    }

    #pragma unroll
    for (int i = 0; i < 4; ++i) {
        int node = n0 + ty * 4 + i;
        bool ok = node < N;
        if (ok) {
            #pragma unroll
            for (int j = 0; j < 4; ++j)
                hbuf[(size_t)node * HD + j * 32 + tx] = acc[i][j];
        }
        #pragma unroll
        for (int j = 0; j < 4; ++j) {
            float vl = acc[i][j] * al[j];
            float vr = acc[i][j] * ar[j];
            #pragma unroll
            for (int o = 1; o < 32; o <<= 1) {
                vl += __shfl_xor(vl, o);
                vr += __shfl_xor(vr, o);
            }
            if (tx == 0 && ok) {
                el[node * NHEAD + j] = vl;
                er[node * NHEAD + j] = vr;
            }
        }
    }
}

// ---------------- CSR build: histogram ----------------
__global__ void hist_k(const int* __restrict__ dst, int* __restrict__ counts, int E) {
    int e = blockIdx.x * 256 + threadIdx.x;
    if (e < E) atomicAdd(&counts[dst[e]], 1);
}

// ---------------- CSR build: single-block exclusive scan ----------------
__global__ __launch_bounds__(1024) void scan_k(const int* __restrict__ counts,
                                               int* __restrict__ row_start, int N) {
    __shared__ int wsum[16];
    __shared__ int ctot;
    __shared__ int carry_s;
    const int t = threadIdx.x;
    const int lane = t & 63, wid = t >> 6;
    if (t == 0) carry_s = 0;
    __syncthreads();
    for (int base = 0; base < N; base += 1024) {
        int i = base + t;
        int v = (i < N) ? counts[i] : 0;
        int x = v;
        #pragma unroll
        for (int o = 1; o < 64; o <<= 1) {
            int y = __shfl_up(x, o);
            if (lane >= o) x += y;
        }
        if (lane == 63) wsum[wid] = x;
        __syncthreads();
        if (t == 0) {
            int s = 0;
            #pragma unroll
            for (int w = 0; w < 16; ++w) { int tmp = wsum[w]; wsum[w] = s; s += tmp; }
            ctot = s;
        }
        __syncthreads();
        int carry = carry_s;
        if (i < N) row_start[i] = carry + wsum[wid] + (x - v);
        __syncthreads();
        if (t == 0) carry_s += ctot;
    }
    if (t == 0) row_start[N] = carry_s;   // == E
}

// ---------------- CSR build: scatter edge srcs into dst-grouped order ----------------
__global__ void scatter_k(const int* __restrict__ src, const int* __restrict__ dst,
                          const int* __restrict__ row_start, int* __restrict__ cursor,
                          int* __restrict__ srcs, int E) {
    int e = blockIdx.x * 256 + threadIdx.x;
    if (e >= E) return;
    int d = dst[e];
    int pos = atomicAdd(&cursor[d], 1);
    srcs[row_start[d] + pos] = src[e];
}

// ---------------- aggregate: one block (128 thr) per dst node, no atomics ----------------
__global__ __launch_bounds__(128) void agg_k(
        const int* __restrict__ row_start, const int* __restrict__ srcs,
        const float* __restrict__ el, const float* __restrict__ er,
        const float* __restrict__ hbuf, const float* __restrict__ bias,
        float* __restrict__ out, int N) {
    __shared__ float ex_lds[CHUNK][NHEAD];
    __shared__ int   s_lds[CHUNK];
    const int d = blockIdx.x;
    const int t = threadIdx.x;       // channel c = t
    const int j = t & 31;            // edge-slot lane for phase C1
    const int hh = t >> 5;           // head (both for C1 and for channel c)
    const int base = row_start[d];
    const int deg  = row_start[d + 1] - base;
    const float erd = er[d * NHEAD + hh];

    float acc = 0.f;   // unnormalized weighted sum for channel t
    float den = 0.f;   // per-lane partial of sum(exp) for head hh

    for (int c0 = 0; c0 < deg; c0 += CHUNK) {
        const int len = min(CHUNK, deg - c0);
        __syncthreads();   // LDS reuse guard vs previous C2
        // C1: threads (j, hh) compute exp-logit for edges c0+j, c0+j+32
        #pragma unroll
        for (int jj = j; jj < CHUNK; jj += 32) {
            if (jj < len) {
                int s = srcs[base + c0 + jj];
                float v = el[s * NHEAD + hh] + erd;
                v = v > 0.f ? v : NEG_SLOPE * v;
                float ex = __expf(v);
                if (hh == 0) s_lds[jj] = s;
                ex_lds[jj][hh] = ex;
                den += ex;
            }
        }
        __syncthreads();
        // C2: all 128 threads accumulate their channel over the chunk's edges
        #pragma unroll 4
        for (int jj = 0; jj < len; ++jj) {
            acc += hbuf[(size_t)s_lds[jj] * HD + t] * ex_lds[jj][hh];
        }
    }

    // reduce den over the 32 lanes of this head group (butterfly keeps all lanes valid)
    #pragma unroll
    for (int o = 1; o < 32; o <<= 1) den += __shfl_xor(den, o);

    float r = 1.0f / fmaxf(den, 1e-9f);
    out[(size_t)d * HD + t] = acc * r + bias[t];
}

extern "C" void kernel_launch(void* const* d_in, const int* in_sizes, int n_in,
                              void* d_out, int out_size, void* d_ws, size_t ws_size,
                              hipStream_t stream) {
    const float* feat   = (const float*)d_in[0];
    const float* fcw    = (const float*)d_in[1];
    const float* attn_l = (const float*)d_in[2];
    const float* attn_r = (const float*)d_in[3];
    const float* bias   = (const float*)d_in[4];
    const int*   src    = (const int*)d_in[5];
    const int*   dst    = (const int*)d_in[6];
    float* out = (float*)d_out;

    const int N = in_sizes[0] / D_IN;
    const int E = in_sizes[5];

    // workspace layout
    float* hbuf      = (float*)d_ws;                       // N*128 f32
    float* el        = hbuf + (size_t)N * HD;              // N*4
    float* er        = el + (size_t)N * NHEAD;             // N*4
    int*   counts    = (int*)(er + (size_t)N * NHEAD);     // N
    int*   cursor    = counts + N;                         // N
    int*   row_start = cursor + N;                         // N+1
    int*   srcs      = row_start + N + 1;                  // E

    zero_k<<<(N + 255) / 256, 256, 0, stream>>>(counts, cursor, N);
    gemm_k<<<(N + 31) / 32, 256, 0, stream>>>(feat, fcw, attn_l, attn_r, hbuf, el, er, N);
    hist_k<<<(E + 255) / 256, 256, 0, stream>>>(dst, counts, E);
    scan_k<<<1, 1024, 0, stream>>>(counts, row_start, N);
    scatter_k<<<(E + 255) / 256, 256, 0, stream>>>(src, dst, row_start, cursor, srcs, E);
    agg_k<<<N, 128, 0, stream>>>(row_start, srcs, el, er, hbuf, bias, out, N);
}

// Round 3
// 301.059 us; speedup vs baseline: 3.5299x; 1.5739x over previous
//
#include <hip/hip_runtime.h>
#include <hip/hip_bf16.h>
#include <math.h>

#define D_IN   256
#define HD     128
#define NHEAD  4
#define NEG_SLOPE 0.2f
#define CHUNK 32

typedef _Float16 h8 __attribute__((ext_vector_type(8)));
typedef _Float16 h4 __attribute__((ext_vector_type(4)));
typedef _Float16 h2 __attribute__((ext_vector_type(2)));
typedef float f4 __attribute__((ext_vector_type(4)));

#define SWZ(row, byte) ((byte) ^ (((row) & 7) << 4))

// ---------------- zero counts ----------------
__global__ void zero_k(int* __restrict__ counts, int N) {
    int i = blockIdx.x * 256 + threadIdx.x;
    if (i < N) counts[i] = 0;
}

// ---------------- GEMM h = feat @ W^T via f16 MFMA (+ fused el/er) ----------------
// block = 256 thr = 4 waves; wave w owns out-channels [32w,32w+32) == head w.
// tile: 64 nodes x 128 out, K=256 staged once in LDS as f16 (swizzled).
__global__ __launch_bounds__(256) void gemm_k(
        const float* __restrict__ feat, const float* __restrict__ fcw,
        const float* __restrict__ attn_l, const float* __restrict__ attn_r,
        unsigned int* __restrict__ hbuf, float* __restrict__ el, float* __restrict__ er,
        int N) {
    __shared__ __align__(16) unsigned char lds_raw[64 * 512];   // 32 KB
    const int t  = threadIdx.x;
    const int l  = t & 63;
    const int w  = t >> 6;          // wave index == head
    const int l4 = l >> 4;          // k-group 0..3
    const int lm = l & 15;
    const int n0 = blockIdx.x * 64;

    // ---- B preload: W rows w*32 + jt*16 + lm, converted to f16 fragments
    h8 breg[2][8];
    #pragma unroll
    for (int jt = 0; jt < 2; ++jt) {
        const float* wrow = fcw + (size_t)(w * 32 + jt * 16 + lm) * D_IN;
        #pragma unroll
        for (int ks = 0; ks < 8; ++ks) {
            int k = ks * 32 + l4 * 8;
            float4 a = *(const float4*)&wrow[k];
            float4 b = *(const float4*)&wrow[k + 4];
            h8 p = {(_Float16)a.x, (_Float16)a.y, (_Float16)a.z, (_Float16)a.w,
                    (_Float16)b.x, (_Float16)b.y, (_Float16)b.z, (_Float16)b.w};
            breg[jt][ks] = p;
        }
    }

    // ---- stage A: feat tile [64][256] -> f16 LDS, XOR-swizzled rows
    #pragma unroll
    for (int i = 0; i < 16; ++i) {
        int idx = t + 256 * i;
        int row = idx >> 6, c4 = idx & 63;          // k = c4*4
        float4 v = make_float4(0.f, 0.f, 0.f, 0.f);
        if (n0 + row < N) v = *(const float4*)&feat[(size_t)(n0 + row) * D_IN + c4 * 4];
        h4 p = {(_Float16)v.x, (_Float16)v.y, (_Float16)v.z, (_Float16)v.w};
        *(h4*)(lds_raw + row * 512 + SWZ(row, c4 * 8)) = p;
    }
    __syncthreads();

    // ---- K-loop: pure LDS reads + MFMA
    f4 acc[4][2] = {};
    #pragma unroll
    for (int ks = 0; ks < 8; ++ks) {
        #pragma unroll
        for (int mt = 0; mt < 4; ++mt) {
            int row = mt * 16 + lm;
            h8 af = *(const h8*)(lds_raw + row * 512 + SWZ(row, (ks * 32 + l4 * 8) * 2));
            acc[mt][0] = __builtin_amdgcn_mfma_f32_16x16x32_f16(af, breg[0][ks], acc[mt][0], 0, 0, 0);
            acc[mt][1] = __builtin_amdgcn_mfma_f32_16x16x32_f16(af, breg[1][ks], acc[mt][1], 0, 0, 0);
        }
    }

    // ---- fused el/er: reduce over the 32 channels of head w per node
    float al[2], ar[2];
    #pragma unroll
    for (int jt = 0; jt < 2; ++jt) {
        al[jt] = attn_l[w * 32 + jt * 16 + lm];
        ar[jt] = attn_r[w * 32 + jt * 16 + lm];
    }
    #pragma unroll
    for (int mt = 0; mt < 4; ++mt) {
        #pragma unroll
        for (int r = 0; r < 4; ++r) {
            float vl = acc[mt][0][r] * al[0] + acc[mt][1][r] * al[1];
            float vr = acc[mt][0][r] * ar[0] + acc[mt][1][r] * ar[1];
            #pragma unroll
            for (int o = 1; o < 16; o <<= 1) {
                vl += __shfl_xor(vl, o);
                vr += __shfl_xor(vr, o);
            }
            int node = n0 + mt * 16 + l4 * 4 + r;
            if (lm == 0 && node < N) {
                el[node * NHEAD + w] = vl;
                er[node * NHEAD + w] = vr;
            }
        }
    }

    // ---- h -> LDS (f16) -> coalesced global dump
    __syncthreads();
    unsigned short* hl = (unsigned short*)lds_raw;   // [64][128] f16
    #pragma unroll
    for (int mt = 0; mt < 4; ++mt)
        #pragma unroll
        for (int jt = 0; jt < 2; ++jt)
            #pragma unroll
            for (int r = 0; r < 4; ++r) {
                int node_local = mt * 16 + l4 * 4 + r;
                int ch = w * 32 + jt * 16 + lm;
                _Float16 hf = (_Float16)acc[mt][jt][r];
                hl[node_local * 128 + ch] = __builtin_bit_cast(unsigned short, hf);
            }
    __syncthreads();
    const unsigned int* hu = (const unsigned int*)lds_raw;   // [64][64] u32
    #pragma unroll
    for (int i = 0; i < 16; ++i) {
        int idx = t + 256 * i;
        int row = idx >> 6, c = idx & 63;
        if (n0 + row < N) hbuf[(size_t)(n0 + row) * 64 + c] = hu[row * 64 + c];
    }
}

// ---------------- CSR build: histogram ----------------
__global__ void hist_k(const int* __restrict__ dst, int* __restrict__ counts, int E) {
    int e = blockIdx.x * 256 + threadIdx.x;
    if (e < E) atomicAdd(&counts[dst[e]], 1);
}

// ---------------- CSR build: single-block vectorized exclusive scan ----------------
__global__ __launch_bounds__(1024) void scan_k(const int* __restrict__ counts,
                                               int* __restrict__ row_start,
                                               int* __restrict__ cursor, int N) {
    __shared__ int wsum[16];
    __shared__ int ctot;
    __shared__ int carry_s;
    const int t = threadIdx.x;
    const int lane = t & 63, wid = t >> 6;
    if (t == 0) carry_s = 0;
    __syncthreads();
    const int nIter = (N + 4095) / 4096;
    for (int it = 0; it < nIter; ++it) {
        int i4 = it * 4096 + t * 4;
        int4 v = make_int4(0, 0, 0, 0);
        if (i4 + 3 < N) v = *(const int4*)&counts[i4];
        else {
            if (i4     < N) v.x = counts[i4];
            if (i4 + 1 < N) v.y = counts[i4 + 1];
            if (i4 + 2 < N) v.z = counts[i4 + 2];
        }
        int s = v.x + v.y + v.z + v.w;
        int x = s;
        #pragma unroll
        for (int o = 1; o < 64; o <<= 1) {
            int y = __shfl_up(x, o);
            if (lane >= o) x += y;
        }
        if (lane == 63) wsum[wid] = x;
        __syncthreads();                                   // A
        if (t == 0) {
            int ss = 0;
            #pragma unroll
            for (int w2 = 0; w2 < 16; ++w2) { int tmp = wsum[w2]; wsum[w2] = ss; ss += tmp; }
            ctot = ss;
        }
        __syncthreads();                                   // B
        int pre = carry_s + wsum[wid] + (x - s);
        int4 rs;
        rs.x = pre;
        rs.y = pre + v.x;
        rs.z = pre + v.x + v.y;
        rs.w = pre + v.x + v.y + v.z;
        if (i4 + 3 < N) {
            *(int4*)&row_start[i4] = rs;
            *(int4*)&cursor[i4]    = rs;
        } else {
            if (i4     < N) { row_start[i4]     = rs.x; cursor[i4]     = rs.x; }
            if (i4 + 1 < N) { row_start[i4 + 1] = rs.y; cursor[i4 + 1] = rs.y; }
            if (i4 + 2 < N) { row_start[i4 + 2] = rs.z; cursor[i4 + 2] = rs.z; }
        }
        __syncthreads();                                   // C
        if (t == 0) carry_s += ctot;
    }
    if (t == 0) row_start[N] = carry_s;
}

// ---------------- CSR build: scatter srcs into dst-grouped order ----------------
__global__ void scatter_k(const int* __restrict__ src, const int* __restrict__ dst,
                          int* __restrict__ cursor, int* __restrict__ srcs, int E) {
    int e = blockIdx.x * 256 + threadIdx.x;
    if (e >= E) return;
    int pos = atomicAdd(&cursor[dst[e]], 1);
    srcs[pos] = src[e];
}

// ---------------- aggregate: one wave (64 thr) per dst node ----------------
__global__ __launch_bounds__(64) void agg_k(
        const int* __restrict__ row_start, const int* __restrict__ srcs,
        const float* __restrict__ el, const float* __restrict__ er,
        const unsigned int* __restrict__ hbuf, const float* __restrict__ bias,
        float* __restrict__ out, int N) {
    __shared__ float ex_lds[CHUNK * NHEAD];
    __shared__ int   s_lds[CHUNK];
    const int d = blockIdx.x;
    const int t = threadIdx.x;      // channel pair (2t, 2t+1); head = t>>4
    const int he = t >> 4;
    const int es = t & 15;
    const int base = row_start[d];
    const int deg  = row_start[d + 1] - base;
    const float erd = er[d * NHEAD + he];

    float2 acc = make_float2(0.f, 0.f);
    float den = 0.f;

    for (int c0 = 0; c0 < deg; c0 += CHUNK) {
        const int len = min(CHUNK, deg - c0);
        __syncthreads();
        #pragma unroll
        for (int jj = es; jj < CHUNK; jj += 16) {
            if (jj < len) {
                int s = srcs[base + c0 + jj];
                float v = el[s * NHEAD + he] + erd;
                v = v > 0.f ? v : NEG_SLOPE * v;
                float ex = __expf(v);
                if (he == 0) s_lds[jj] = s;
                ex_lds[jj * NHEAD + he] = ex;
                den += ex;
            }
        }
        __syncthreads();
        #pragma unroll 4
        for (int jj = 0; jj < len; ++jj) {
            int s = s_lds[jj];
            unsigned int hv = hbuf[(size_t)s * 64 + t];
            h2 hh = __builtin_bit_cast(h2, hv);
            float exv = ex_lds[jj * NHEAD + he];
            acc.x += (float)hh[0] * exv;
            acc.y += (float)hh[1] * exv;
        }
    }

    #pragma unroll
    for (int o = 1; o < 16; o <<= 1) den += __shfl_xor(den, o);
    float r = 1.0f / fmaxf(den, 1e-9f);
    float2 b2 = *(const float2*)&bias[2 * t];
    float2 o2 = make_float2(acc.x * r + b2.x, acc.y * r + b2.y);
    *(float2*)&out[(size_t)d * HD + 2 * t] = o2;
}

extern "C" void kernel_launch(void* const* d_in, const int* in_sizes, int n_in,
                              void* d_out, int out_size, void* d_ws, size_t ws_size,
                              hipStream_t stream) {
    const float* feat   = (const float*)d_in[0];
    const float* fcw    = (const float*)d_in[1];
    const float* attn_l = (const float*)d_in[2];
    const float* attn_r = (const float*)d_in[3];
    const float* bias   = (const float*)d_in[4];
    const int*   src    = (const int*)d_in[5];
    const int*   dst    = (const int*)d_in[6];
    float* out = (float*)d_out;

    const int N = in_sizes[0] / D_IN;
    const int E = in_sizes[5];

    unsigned int* hbuf = (unsigned int*)d_ws;                 // N*64 u32 (f16 pairs)
    float* el        = (float*)(hbuf + (size_t)N * 64);       // N*4
    float* er        = el + (size_t)N * NHEAD;                // N*4
    int*   counts    = (int*)(er + (size_t)N * NHEAD);        // N
    int*   cursor    = counts + N;                            // N
    int*   row_start = cursor + N;                            // N+1
    int*   srcs      = row_start + N + 1;                     // E

    zero_k<<<(N + 255) / 256, 256, 0, stream>>>(counts, N);
    hist_k<<<(E + 255) / 256, 256, 0, stream>>>(dst, counts, E);
    scan_k<<<1, 1024, 0, stream>>>(counts, row_start, cursor, N);
    scatter_k<<<(E + 255) / 256, 256, 0, stream>>>(src, dst, cursor, srcs, E);
    gemm_k<<<(N + 63) / 64, 256, 0, stream>>>(feat, fcw, attn_l, attn_r, hbuf, el, er, N);
    agg_k<<<N, 64, 0, stream>>>(row_start, srcs, el, er, hbuf, bias, out, N);
}

// Round 4
// 155.213 us; speedup vs baseline: 6.8468x; 1.9397x over previous
//
#include <hip/hip_runtime.h>
#include <hip/hip_bf16.h>
#include <math.h>

#define D_IN   256
#define HD     128
#define NHEAD  4
#define NEG_SLOPE 0.2f
#define CHUNK 32
#define MAXB  1024      // max dst-buckets (N <= 65536)

typedef _Float16 h8 __attribute__((ext_vector_type(8)));
typedef _Float16 h4 __attribute__((ext_vector_type(4)));
typedef _Float16 h2 __attribute__((ext_vector_type(2)));
typedef float f4 __attribute__((ext_vector_type(4)));

#define SWZ(row, byte) ((byte) ^ (((row) & 7) << 4))

// ---------------- zero bucket counts ----------------
__global__ void zero_k(int* __restrict__ bcnt, int B) {
    int i = blockIdx.x * 256 + threadIdx.x;
    if (i < B) bcnt[i] = 0;
}

// ---------------- bucket histogram (LDS-aggregated) ----------------
__global__ __launch_bounds__(256) void bhist_k(const int* __restrict__ dst,
                                               int* __restrict__ bcnt, int E, int B) {
    __shared__ int lcnt[MAXB];
    const int t = threadIdx.x;
    for (int i = t; i < B; i += 256) lcnt[i] = 0;
    __syncthreads();
    const int base = blockIdx.x * 4096;
    const int end = min(base + 4096, E);
    for (int i = base + t; i < end; i += 256)
        atomicAdd(&lcnt[dst[i] >> 6], 1);
    __syncthreads();
    for (int i = t; i < B; i += 256)
        if (lcnt[i]) atomicAdd(&bcnt[i], lcnt[i]);
}

// ---------------- bucket scan (single block, B <= 1024) ----------------
__global__ __launch_bounds__(1024) void bscan_k(const int* __restrict__ bcnt,
                                                int* __restrict__ bbase,
                                                int* __restrict__ gcur,
                                                int* __restrict__ row_start,
                                                int B, int N, int E) {
    __shared__ int wsum[16];
    const int t = threadIdx.x, lane = t & 63, wid = t >> 6;
    int v = (t < B) ? bcnt[t] : 0;
    int x = v;
    #pragma unroll
    for (int o = 1; o < 64; o <<= 1) {
        int y = __shfl_up(x, o);
        if (lane >= o) x += y;
    }
    if (lane == 63) wsum[wid] = x;
    __syncthreads();
    if (t == 0) {
        int s = 0;
        #pragma unroll
        for (int w = 0; w < 16; ++w) { int tmp = wsum[w]; wsum[w] = s; s += tmp; }
    }
    __syncthreads();
    int excl = wsum[wid] + x - v;
    if (t < B) { bbase[t] = excl; gcur[t] = excl; }
    if (t == 0) { bbase[B] = E; row_start[N] = E; }
}

// ---------------- bin edges into bucket-contiguous regions ----------------
__global__ __launch_bounds__(256) void bin_k(const int* __restrict__ src,
                                             const int* __restrict__ dst,
                                             int* __restrict__ gcur,
                                             unsigned int* __restrict__ pairs,
                                             int E, int B) {
    __shared__ int lcnt[MAXB];
    __shared__ int lbase[MAXB];
    const int t = threadIdx.x;
    for (int i = t; i < B; i += 256) lcnt[i] = 0;
    __syncthreads();
    const int base = blockIdx.x * 4096;
    int sv[16], dv[16];
    #pragma unroll
    for (int k = 0; k < 16; ++k) {
        int idx = base + k * 256 + t;
        if (idx < E) {
            sv[k] = src[idx];
            dv[k] = dst[idx];
            atomicAdd(&lcnt[dv[k] >> 6], 1);
        } else dv[k] = -1;
    }
    __syncthreads();
    for (int i = t; i < B; i += 256) {
        int c = lcnt[i];
        lbase[i] = c ? atomicAdd(&gcur[i], c) : 0;
        lcnt[i] = 0;
    }
    __syncthreads();
    #pragma unroll
    for (int k = 0; k < 16; ++k) {
        if (dv[k] >= 0) {
            int b = dv[k] >> 6;
            int r = atomicAdd(&lcnt[b], 1);
            pairs[lbase[b] + r] = ((unsigned int)sv[k] << 6) | (unsigned int)(dv[k] & 63);
        }
    }
}

// ---------------- per-bucket: row_start + final srcs order, all-LDS cursors ----------------
__global__ __launch_bounds__(256) void bucket_k(const unsigned int* __restrict__ pairs,
                                                const int* __restrict__ bbase,
                                                int* __restrict__ row_start,
                                                int* __restrict__ srcs, int N) {
    __shared__ int cnt64[64];
    __shared__ int base64[64];
    const int b = blockIdx.x;
    const int t = threadIdx.x;
    const int lo = bbase[b], hi = bbase[b + 1];
    if (t < 64) cnt64[t] = 0;
    __syncthreads();
    for (int i = lo + t; i < hi; i += 256)
        atomicAdd(&cnt64[pairs[i] & 63], 1);
    __syncthreads();
    if (t < 64) {
        int v = cnt64[t];
        int x = v;
        #pragma unroll
        for (int o = 1; o < 64; o <<= 1) {
            int y = __shfl_up(x, o);
            if (t >= o) x += y;
        }
        int excl = lo + x - v;
        base64[t] = excl;
        int d = b * 64 + t;
        if (d < N) row_start[d] = excl;
        cnt64[t] = 0;
    }
    __syncthreads();
    for (int i = lo + t; i < hi; i += 256) {
        unsigned int p = pairs[i];
        int ld = p & 63;
        int r = atomicAdd(&cnt64[ld], 1);
        srcs[base64[ld] + r] = (int)(p >> 6);
    }
}

// ---------------- GEMM h = feat @ W^T via f16 MFMA (+ fused el/er) ----------------
__global__ __launch_bounds__(256) void gemm_k(
        const float* __restrict__ feat, const float* __restrict__ fcw,
        const float* __restrict__ attn_l, const float* __restrict__ attn_r,
        unsigned int* __restrict__ hbuf, float* __restrict__ el, float* __restrict__ er,
        int N) {
    __shared__ __align__(16) unsigned char lds_raw[64 * 512];   // 32 KB
    const int t  = threadIdx.x;
    const int l  = t & 63;
    const int w  = t >> 6;          // wave index == head
    const int l4 = l >> 4;          // k-group 0..3
    const int lm = l & 15;
    const int n0 = blockIdx.x * 64;

    h8 breg[2][8];
    #pragma unroll
    for (int jt = 0; jt < 2; ++jt) {
        const float* wrow = fcw + (size_t)(w * 32 + jt * 16 + lm) * D_IN;
        #pragma unroll
        for (int ks = 0; ks < 8; ++ks) {
            int k = ks * 32 + l4 * 8;
            float4 a = *(const float4*)&wrow[k];
            float4 b = *(const float4*)&wrow[k + 4];
            h8 p = {(_Float16)a.x, (_Float16)a.y, (_Float16)a.z, (_Float16)a.w,
                    (_Float16)b.x, (_Float16)b.y, (_Float16)b.z, (_Float16)b.w};
            breg[jt][ks] = p;
        }
    }

    #pragma unroll
    for (int i = 0; i < 16; ++i) {
        int idx = t + 256 * i;
        int row = idx >> 6, c4 = idx & 63;
        float4 v = make_float4(0.f, 0.f, 0.f, 0.f);
        if (n0 + row < N) v = *(const float4*)&feat[(size_t)(n0 + row) * D_IN + c4 * 4];
        h4 p = {(_Float16)v.x, (_Float16)v.y, (_Float16)v.z, (_Float16)v.w};
        *(h4*)(lds_raw + row * 512 + SWZ(row, c4 * 8)) = p;
    }
    __syncthreads();

    f4 acc[4][2] = {};
    #pragma unroll
    for (int ks = 0; ks < 8; ++ks) {
        #pragma unroll
        for (int mt = 0; mt < 4; ++mt) {
            int row = mt * 16 + lm;
            h8 af = *(const h8*)(lds_raw + row * 512 + SWZ(row, (ks * 32 + l4 * 8) * 2));
            acc[mt][0] = __builtin_amdgcn_mfma_f32_16x16x32_f16(af, breg[0][ks], acc[mt][0], 0, 0, 0);
            acc[mt][1] = __builtin_amdgcn_mfma_f32_16x16x32_f16(af, breg[1][ks], acc[mt][1], 0, 0, 0);
        }
    }

    float al[2], ar[2];
    #pragma unroll
    for (int jt = 0; jt < 2; ++jt) {
        al[jt] = attn_l[w * 32 + jt * 16 + lm];
        ar[jt] = attn_r[w * 32 + jt * 16 + lm];
    }
    #pragma unroll
    for (int mt = 0; mt < 4; ++mt) {
        #pragma unroll
        for (int r = 0; r < 4; ++r) {
            float vl = acc[mt][0][r] * al[0] + acc[mt][1][r] * al[1];
            float vr = acc[mt][0][r] * ar[0] + acc[mt][1][r] * ar[1];
            #pragma unroll
            for (int o = 1; o < 16; o <<= 1) {
                vl += __shfl_xor(vl, o);
                vr += __shfl_xor(vr, o);
            }
            int node = n0 + mt * 16 + l4 * 4 + r;
            if (lm == 0 && node < N) {
                el[node * NHEAD + w] = vl;
                er[node * NHEAD + w] = vr;
            }
        }
    }

    __syncthreads();
    unsigned short* hl = (unsigned short*)lds_raw;
    #pragma unroll
    for (int mt = 0; mt < 4; ++mt)
        #pragma unroll
        for (int jt = 0; jt < 2; ++jt)
            #pragma unroll
            for (int r = 0; r < 4; ++r) {
                int node_local = mt * 16 + l4 * 4 + r;
                int ch = w * 32 + jt * 16 + lm;
                _Float16 hf = (_Float16)acc[mt][jt][r];
                hl[node_local * 128 + ch] = __builtin_bit_cast(unsigned short, hf);
            }
    __syncthreads();
    const unsigned int* hu = (const unsigned int*)lds_raw;
    #pragma unroll
    for (int i = 0; i < 16; ++i) {
        int idx = t + 256 * i;
        int row = idx >> 6, c = idx & 63;
        if (n0 + row < N) hbuf[(size_t)(n0 + row) * 64 + c] = hu[row * 64 + c];
    }
}

// ---------------- aggregate: one wave (64 thr) per dst node ----------------
__global__ __launch_bounds__(64) void agg_k(
        const int* __restrict__ row_start, const int* __restrict__ srcs,
        const float* __restrict__ el, const float* __restrict__ er,
        const unsigned int* __restrict__ hbuf, const float* __restrict__ bias,
        float* __restrict__ out, int N) {
    __shared__ float ex_lds[CHUNK * NHEAD];
    __shared__ int   s_lds[CHUNK];
    const int d = blockIdx.x;
    const int t = threadIdx.x;
    const int he = t >> 4;
    const int es = t & 15;
    const int base = row_start[d];
    const int deg  = row_start[d + 1] - base;
    const float erd = er[d * NHEAD + he];

    float2 acc = make_float2(0.f, 0.f);
    float den = 0.f;

    for (int c0 = 0; c0 < deg; c0 += CHUNK) {
        const int len = min(CHUNK, deg - c0);
        __syncthreads();
        #pragma unroll
        for (int jj = es; jj < CHUNK; jj += 16) {
            if (jj < len) {
                int s = srcs[base + c0 + jj];
                float v = el[s * NHEAD + he] + erd;
                v = v > 0.f ? v : NEG_SLOPE * v;
                float ex = __expf(v);
                if (he == 0) s_lds[jj] = s;
                ex_lds[jj * NHEAD + he] = ex;
                den += ex;
            }
        }
        __syncthreads();
        #pragma unroll 4
        for (int jj = 0; jj < len; ++jj) {
            int s = s_lds[jj];
            unsigned int hv = hbuf[(size_t)s * 64 + t];
            h2 hh = __builtin_bit_cast(h2, hv);
            float exv = ex_lds[jj * NHEAD + he];
            acc.x += (float)hh[0] * exv;
            acc.y += (float)hh[1] * exv;
        }
    }

    #pragma unroll
    for (int o = 1; o < 16; o <<= 1) den += __shfl_xor(den, o);
    float r = 1.0f / fmaxf(den, 1e-9f);
    float2 b2 = *(const float2*)&bias[2 * t];
    float2 o2 = make_float2(acc.x * r + b2.x, acc.y * r + b2.y);
    *(float2*)&out[(size_t)d * HD + 2 * t] = o2;
}

extern "C" void kernel_launch(void* const* d_in, const int* in_sizes, int n_in,
                              void* d_out, int out_size, void* d_ws, size_t ws_size,
                              hipStream_t stream) {
    const float* feat   = (const float*)d_in[0];
    const float* fcw    = (const float*)d_in[1];
    const float* attn_l = (const float*)d_in[2];
    const float* attn_r = (const float*)d_in[3];
    const float* bias   = (const float*)d_in[4];
    const int*   src    = (const int*)d_in[5];
    const int*   dst    = (const int*)d_in[6];
    float* out = (float*)d_out;

    const int N = in_sizes[0] / D_IN;
    const int E = in_sizes[5];
    const int B = (N + 63) >> 6;    // dst-buckets of 64 nodes

    unsigned int* hbuf = (unsigned int*)d_ws;                 // N*64 u32 (f16 pairs)
    float* el        = (float*)(hbuf + (size_t)N * 64);       // N*4
    float* er        = el + (size_t)N * NHEAD;                // N*4
    int*   row_start = (int*)(er + (size_t)N * NHEAD);        // N+1
    int*   srcs      = row_start + N + 1;                     // E
    unsigned int* pairs = (unsigned int*)(srcs + E);          // E
    int*   bbase     = (int*)(pairs + E);                     // B+1
    int*   bcnt      = bbase + B + 1;                         // B
    int*   gcur      = bcnt + B;                              // B

    const int ebl = (E + 4095) / 4096;   // edge blocks (4096 edges each)

    zero_k<<<(B + 255) / 256, 256, 0, stream>>>(bcnt, B);
    bhist_k<<<ebl, 256, 0, stream>>>(dst, bcnt, E, B);
    bscan_k<<<1, 1024, 0, stream>>>(bcnt, bbase, gcur, row_start, B, N, E);
    bin_k<<<ebl, 256, 0, stream>>>(src, dst, gcur, pairs, E, B);
    bucket_k<<<B, 256, 0, stream>>>(pairs, bbase, row_start, srcs, N);
    gemm_k<<<(N + 63) / 64, 256, 0, stream>>>(feat, fcw, attn_l, attn_r, hbuf, el, er, N);
    agg_k<<<N, 64, 0, stream>>>(row_start, srcs, el, er, hbuf, bias, out, N);
}